// Round 17
// baseline (843.701 us; speedup 1.0000x reference)
//
#include <hip/hip_runtime.h>
#include <hip/hip_bf16.h>
#include <math.h>

#define L 4096      // 16^3
#define NC 64
#define BZ 4
#define PS 17       // padded z-stride (bank-conflict-free)
#define PXD 272     // 16*PS
#define EBC 82      // smtp LDS row stride

typedef __attribute__((ext_vector_type(8))) short bf16x8;
typedef __attribute__((ext_vector_type(4))) float f32x4;

__device__ inline unsigned short f2bf(float f) {
    unsigned int u = __float_as_uint(f);
    return (unsigned short)((u + 0x7fffu + ((u >> 16) & 1u)) >> 16);   // RNE
}
__device__ inline float bf2f(unsigned int u) { return __uint_as_float(u << 16); }
__device__ inline void unpack8(uint4 v, float* f) {
    f[0] = bf2f(v.x & 0xffffu); f[1] = bf2f(v.x >> 16);
    f[2] = bf2f(v.y & 0xffffu); f[3] = bf2f(v.y >> 16);
    f[4] = bf2f(v.z & 0xffffu); f[5] = bf2f(v.z >> 16);
    f[6] = bf2f(v.w & 0xffffu); f[7] = bf2f(v.w >> 16);
}
__device__ inline uint4 pack8(const float* f) {
    uint4 v;
    v.x = (unsigned)f2bf(f[0]) | ((unsigned)f2bf(f[1]) << 16);
    v.y = (unsigned)f2bf(f[2]) | ((unsigned)f2bf(f[3]) << 16);
    v.z = (unsigned)f2bf(f[4]) | ((unsigned)f2bf(f[5]) << 16);
    v.w = (unsigned)f2bf(f[6]) | ((unsigned)f2bf(f[7]) << 16);
    return v;
}

// ---------------------------------------------------------------------------
// f32 3-axis box filter helpers (k_stats / k_tbox only)
// ---------------------------------------------------------------------------
__device__ void box3_pad(float* A, float* B, int tid, float out[16]) {
    int x = tid >> 4, y = tid & 15;
    int base = x * PXD + y * PS;
    float t[16];
    {
        float line[16];
        #pragma unroll
        for (int z = 0; z < 16; z++) line[z] = A[base + z];
        #pragma unroll
        for (int z = 0; z < 16; z++) {
            float s = line[z];
            if (z > 0)  s += line[z - 1];
            if (z < 15) s += line[z + 1];
            t[z] = s;
        }
    }
    #pragma unroll
    for (int z = 0; z < 16; z++) B[base + z] = t[z];
    __syncthreads();
    #pragma unroll
    for (int z = 0; z < 16; z++) {
        float s = B[base + z];
        if (y > 0)  s += B[base - PS + z];
        if (y < 15) s += B[base + PS + z];
        t[z] = s;
    }
    __syncthreads();
    #pragma unroll
    for (int z = 0; z < 16; z++) A[base + z] = t[z];
    __syncthreads();
    #pragma unroll
    for (int z = 0; z < 16; z++) {
        float s = A[base + z];
        if (x > 0)  s += A[base - PXD + z];
        if (x < 15) s += A[base + PXD + z];
        out[z] = s;
    }
    __syncthreads();
}
__device__ inline void fill_pad(float* A, const float* __restrict__ g, int tid) {
    for (int i = tid; i < 4096; i += 256)
        A[(i >> 8) * PXD + ((i >> 4) & 15) * PS + (i & 15)] = g[i];
    __syncthreads();
}

// ---------------------------------------------------------------------------
// K1: bg=fm*(1-mask); bf16 copies bgT[l][c], fmT[p][c], bgh[c][p]; f32 sums.
// ---------------------------------------------------------------------------
__global__ void k_prep(const float* __restrict__ fm, const float* __restrict__ mask,
                       unsigned short* __restrict__ bgT, unsigned short* __restrict__ fmT,
                       unsigned short* __restrict__ bgh,
                       float* __restrict__ sfm, float* __restrict__ sbg,
                       float* __restrict__ qbg) {
    int b = blockIdx.y;
    int p = blockIdx.x * 256 + threadIdx.x;
    float m = mask[b * L + p];
    float w = 1.f - m;
    float s_f = 0.f, s_b = 0.f, q_b = 0.f;
    const float* fmb = fm + (size_t)b * NC * L + p;
    unsigned short* bghb = bgh + (size_t)b * NC * L + p;
    unsigned short tA[NC], tB[NC];
    #pragma unroll
    for (int c = 0; c < NC; c++) {
        float f = fmb[(size_t)c * L];
        float g = f * w;
        s_f += f; s_b += g; q_b += g * g;
        unsigned short gb = f2bf(g);
        tA[c] = gb;
        tB[c] = f2bf(f);
        bghb[(size_t)c * L] = gb;
    }
    unsigned short* bgTb = bgT + (size_t)b * L * NC + (size_t)p * NC;
    unsigned short* fmTb = fmT + (size_t)b * L * NC + (size_t)p * NC;
    #pragma unroll
    for (int i = 0; i < 8; i++) {
        ((uint4*)bgTb)[i] = ((const uint4*)tA)[i];
        ((uint4*)fmTb)[i] = ((const uint4*)tB)[i];
    }
    sfm[b * L + p] = s_f;
    sbg[b * L + p] = s_b;
    qbg[b * L + p] = q_b;
}

// ---------------------------------------------------------------------------
// K2: invn = rsqrt(box3(qbg)+2e-7*box3(sbg)+1728e-14); s2fm = box3(box3(sfm))
// ---------------------------------------------------------------------------
__global__ void k_stats(const float* __restrict__ sfm, const float* __restrict__ sbg,
                        const float* __restrict__ qbg,
                        float* __restrict__ invn, float* __restrict__ s2fm) {
    __shared__ float A[16 * PXD];
    __shared__ float Bf[16 * PXD];
    int b = blockIdx.x;
    int tid = threadIdx.x;
    int x = tid >> 4, y = tid & 15;
    float Q[16], Sb[16], r[16];

    fill_pad(A, qbg + b * L, tid);
    box3_pad(A, Bf, tid, Q);
    fill_pad(A, sbg + b * L, tid);
    box3_pad(A, Bf, tid, Sb);
    for (int z = 0; z < 16; z++) {
        float denom = Q[z] + 2e-7f * Sb[z] + 1.728e-11f;
        invn[b * L + x * 256 + y * 16 + z] = rsqrtf(denom);
    }
    fill_pad(A, sfm + b * L, tid);
    box3_pad(A, Bf, tid, r);
    int base = x * PXD + y * PS;
    #pragma unroll
    for (int z = 0; z < 16; z++) A[base + z] = r[z];
    __syncthreads();
    box3_pad(A, Bf, tid, r);
    for (int z = 0; z < 16; z++) s2fm[b * L + x * 256 + y * 16 + z] = r[z];
}

// ---------------------------------------------------------------------------
// K3: MFMA Gram + fused diag-z+box-z (9-term LDS read, single sync), bf16 out.
// ---------------------------------------------------------------------------
__global__ __launch_bounds__(256) void k_gram(const unsigned short* __restrict__ bgT,
                                              const unsigned short* __restrict__ fmT,
                                              unsigned short* __restrict__ slab,
                                              size_t slotU, int b0) {
    int zi = blockIdx.z, b = b0 + zi;
    unsigned short* Czz = slab + (size_t)zi * slotU;
    const unsigned short* bgTb = bgT + (size_t)b * L * NC;
    const unsigned short* fmTb = fmT + (size_t)b * L * NC;
    __shared__ float Gs[64][65];
    int tid = threadIdx.x;
    int l0 = blockIdx.y * 64, p0 = blockIdx.x * 64;
    int w = tid >> 6, lane = tid & 63;
    int rr = lane & 15, kg = lane >> 4;

    bf16x8 a0 = *(const bf16x8*)&bgTb[(size_t)(l0 + w * 16 + rr) * NC + kg * 8];
    bf16x8 a1 = *(const bf16x8*)&bgTb[(size_t)(l0 + w * 16 + rr) * NC + 32 + kg * 8];
    f32x4 acc[4];
    #pragma unroll
    for (int pt = 0; pt < 4; pt++) {
        bf16x8 bb0 = *(const bf16x8*)&fmTb[(size_t)(p0 + pt * 16 + rr) * NC + kg * 8];
        bf16x8 bb1 = *(const bf16x8*)&fmTb[(size_t)(p0 + pt * 16 + rr) * NC + 32 + kg * 8];
        f32x4 z; z[0] = 0.f; z[1] = 0.f; z[2] = 0.f; z[3] = 0.f;
        z = __builtin_amdgcn_mfma_f32_16x16x32_bf16(a0, bb0, z, 0, 0, 0);
        z = __builtin_amdgcn_mfma_f32_16x16x32_bf16(a1, bb1, z, 0, 0, 0);
        acc[pt] = z;
    }
    #pragma unroll
    for (int pt = 0; pt < 4; pt++)
        #pragma unroll
        for (int r = 0; r < 4; r++)
            Gs[w * 16 + kg * 4 + r][pt * 16 + rr] = acc[pt][r];
    __syncthreads();

    int row = tid >> 2, cg = (tid & 3) * 16;
    int lz = row & 15;
    float wl0 = lz > 0 ? 1.f : 0.f, wl2 = lz < 15 ? 1.f : 0.f;
    int rm = row > 0 ? row - 1 : 0, rp = row < 63 ? row + 1 : 63;
    float o[16];
    #pragma unroll
    for (int k = 0; k < 16; k++) {
        float v = 0.f;
        #pragma unroll
        for (int e = -1; e <= 1; e++) {
            if (k + e < 0 || k + e > 15) continue;
            #pragma unroll
            for (int d = -1; d <= 1; d++) {
                if (k + e + d < 0 || k + e + d > 15) continue;
                int col = cg + k + e + d;
                if (d == 0)       v += Gs[row][col];
                else if (d == -1) v += wl0 * Gs[rm][col];
                else              v += wl2 * Gs[rp][col];
            }
        }
        o[k] = v;
    }
    uint4* dst = (uint4*)&Czz[(size_t)(l0 + row) * L + p0 + cg];
    dst[0] = pack8(o);
    dst[1] = pack8(o + 8);
}

// ---------------------------------------------------------------------------
// K4: per l-row diag-y/x via 3-tap staged clamped loads (proven no-spill),
//     box-y via shfl, box-x via LDS, logit+exp; rows l and l+16 per block.
//     Block->row map: each XCD owns one ly-pair (ly=2*xcd), lx innermost ->
//     concurrent tap working set ~4MB, fits per-XCD L2.
// ---------------------------------------------------------------------------
__global__ __launch_bounds__(256, 4) void k_rowE(unsigned short* __restrict__ slab,
                                                 size_t slotU,
                                                 const float* __restrict__ s2fm,
                                                 const float* __restrict__ invn, int b0) {
    __shared__ float A[16 * PXD];
    int zi = blockIdx.z, b = b0 + zi;
    const unsigned short* Czz = slab + (size_t)zi * slotU;
    unsigned short* E = slab + (size_t)zi * slotU + (size_t)L * L;
    int bx = blockIdx.x;
    int xcd = bx & 7;
    int j = bx >> 3;                    // [0,256)
    int jlx = j & 15, jlz = j >> 4;
    int lbase = jlx * 256 + (2 * xcd) * 16 + jlz;   // pairs (lbase, lbase+16)
    int tid = threadIdx.x;
    int px = tid >> 4, py = tid & 15;

    #pragma unroll 1
    for (int sub = 0; sub < 2; sub++) {
        int l = lbase + 16 * sub;
        int lx = l >> 8, ly = (l >> 4) & 15;
        int own = l * L + px * 256 + py * 16;

        float c[16];
        #pragma unroll
        for (int z = 0; z < 16; z++) c[z] = 0.f;

        #pragma unroll
        for (int gx = 0; gx < 3; gx++) {
            int dx = gx - 1;
            uint4 s0[3], s1[3];
            float w3[3];
            #pragma unroll
            for (int gy = 0; gy < 3; gy++) {
                int dy = gy - 1;
                bool ok = (unsigned)(lx + dx) < 16u && (unsigned)(px + dx) < 16u &&
                          (unsigned)(ly + dy) < 16u && (unsigned)(py + dy) < 16u;
                int off = ok ? ((l + dy * 16 + dx * 256) * L + (px + dx) * 256 + (py + dy) * 16)
                             : own;
                const uint4* s4 = (const uint4*)(Czz + off);
                s0[gy] = s4[0];
                s1[gy] = s4[1];
                w3[gy] = ok ? 1.f : 0.f;
            }
            #pragma unroll
            for (int gy = 0; gy < 3; gy++) {
                float f[16];
                unpack8(s0[gy], f);
                unpack8(s1[gy], f + 8);
                #pragma unroll
                for (int z = 0; z < 16; z++) c[z] += w3[gy] * f[z];
            }
        }
        // box-y via shuffle (py±1 == lane±1)
        float t16[16];
        #pragma unroll
        for (int z = 0; z < 16; z++) {
            float up = __shfl_up(c[z], 1);
            float dn = __shfl_down(c[z], 1);
            float s = c[z];
            if (py > 0)  s += up;
            if (py < 15) s += dn;
            t16[z] = s;
        }
        int base = px * PXD + py * PS;
        #pragma unroll
        for (int z = 0; z < 16; z++) A[base + z] = t16[z];
        __syncthreads();
        float inl = invn[(size_t)b * L + l];
        const float* s2 = s2fm + (size_t)b * L + px * 256 + py * 16;
        float o[16];
        #pragma unroll
        for (int z = 0; z < 16; z++) {      // box-x + logit + exp
            float s = A[base + z];
            if (px > 0)  s += A[base - PXD + z];
            if (px < 15) s += A[base + PXD + z];
            o[z] = __expf((s + 1e-7f * s2[z]) * inl);
        }
        uint4* dst = (uint4*)&E[own];
        dst[0] = pack8(o);
        dst[1] = pack8(o + 8);
        __syncthreads();                    // A reused next iteration
    }
}

// ---------------------------------------------------------------------------
// K5: column sums of E: staged/unrolled loads, partials [64][L] into slot A.
// ---------------------------------------------------------------------------
__global__ void k_colstat_part(unsigned short* __restrict__ slab, size_t slotU,
                               const float* __restrict__ invn, int b0) {
    int zi = blockIdx.z, b = b0 + zi;
    const unsigned short* E = slab + (size_t)zi * slotU + (size_t)L * L;
    float* ps = (float*)(slab + (size_t)zi * slotU);
    float* psi = ps + 64 * (size_t)L;
    int p8 = (blockIdx.x * 256 + threadIdx.x) * 8;
    int lc = blockIdx.y;
    const float* inv = invn + (size_t)b * L + lc * 64;
    float S[8], SI[8];
    #pragma unroll
    for (int j = 0; j < 8; j++) { S[j] = 0.f; SI[j] = 0.f; }
    const unsigned short* eb = E + (size_t)lc * 64 * L + p8;
    for (int i = 0; i < 64; i += 4) {
        uint4 va = *(const uint4*)(eb + (size_t)(i + 0) * L);
        uint4 vb = *(const uint4*)(eb + (size_t)(i + 1) * L);
        uint4 vc = *(const uint4*)(eb + (size_t)(i + 2) * L);
        uint4 vd = *(const uint4*)(eb + (size_t)(i + 3) * L);
        float f[8];
        float iv;
        unpack8(va, f); iv = inv[i];
        #pragma unroll
        for (int j = 0; j < 8; j++) { S[j] += f[j]; SI[j] += f[j] * iv; }
        unpack8(vb, f); iv = inv[i + 1];
        #pragma unroll
        for (int j = 0; j < 8; j++) { S[j] += f[j]; SI[j] += f[j] * iv; }
        unpack8(vc, f); iv = inv[i + 2];
        #pragma unroll
        for (int j = 0; j < 8; j++) { S[j] += f[j]; SI[j] += f[j] * iv; }
        unpack8(vd, f); iv = inv[i + 3];
        #pragma unroll
        for (int j = 0; j < 8; j++) { S[j] += f[j]; SI[j] += f[j] * iv; }
    }
    float4* d0 = (float4*)(ps + (size_t)lc * L + p8);
    float4* d1 = (float4*)(psi + (size_t)lc * L + p8);
    d0[0] = make_float4(S[0], S[1], S[2], S[3]);
    d0[1] = make_float4(S[4], S[5], S[6], S[7]);
    d1[0] = make_float4(SI[0], SI[1], SI[2], SI[3]);
    d1[1] = make_float4(SI[4], SI[5], SI[6], SI[7]);
}

__global__ void k_colstat_merge(unsigned short* __restrict__ slab, size_t slotU,
                                float* __restrict__ csi, float* __restrict__ Tarr, int b0) {
    int zi = blockIdx.z, b = b0 + zi;
    const float* ps = (const float*)(slab + (size_t)zi * slotU);
    const float* psi = ps + 64 * (size_t)L;
    int p = blockIdx.x * 256 + threadIdx.x;
    float s = 0.f, si = 0.f;
    for (int i = 0; i < 64; i++) { s += ps[(size_t)i * L + p]; si += psi[(size_t)i * L + p]; }
    float inv = 1.f / s;
    csi[(size_t)b * L + p] = inv;
    Tarr[(size_t)b * L + p] = si * inv;
}

__global__ void k_tbox(const float* __restrict__ Tarr, float* __restrict__ Tbox, int b0) {
    __shared__ float A[16 * PXD];
    __shared__ float Bf[16 * PXD];
    int b = b0 + blockIdx.z;
    int tid = threadIdx.x;
    fill_pad(A, Tarr + (size_t)b * L, tid);
    float res[16];
    box3_pad(A, Bf, tid, res);
    int x = tid >> 4, y = tid & 15;
    for (int z = 0; z < 16; z++) Tbox[(size_t)b * L + x * 256 + y * 16 + z] = res[z];
}

// ---------------------------------------------------------------------------
// K6 (fused): softmax-apply + diag-z + TRANSPOSE in one tile pass:
//   At[p][m] = sum_dz w * E[m+dz, p+dz] * csi[p+dz] * invn[m+dz]
// ---------------------------------------------------------------------------
__global__ __launch_bounds__(256) void k_smtp(unsigned short* __restrict__ slab,
                                              size_t slotU,
                                              const float* __restrict__ csi,
                                              const float* __restrict__ invn, int b0) {
    __shared__ float Eb[66 * EBC];
    __shared__ float AZ[64][65];
    __shared__ float csL[66];
    __shared__ float inL[66];
    int zi = blockIdx.z, b = b0 + zi;
    const unsigned short* E = slab + (size_t)zi * slotU + (size_t)L * L;
    unsigned short* At = slab + (size_t)zi * slotU;
    int p0 = blockIdx.x * 64, m0 = blockIdx.y * 64;
    int tid = threadIdx.x;

    for (int s = tid; s < 660; s += 256) {
        int r = s / 10, q = s - r * 10;
        int gm = m0 + r - 1; gm = gm < 0 ? 0 : (gm > 4095 ? 4095 : gm);
        int gp = p0 - 8 + q * 8; gp = gp < 0 ? 0 : (gp > 4088 ? 4088 : gp);
        uint4 v = *(const uint4*)(E + (size_t)gm * L + gp);
        float f[8]; unpack8(v, f);
        #pragma unroll
        for (int k = 0; k < 8; k++) Eb[r * EBC + q * 8 + k] = f[k];
    }
    for (int i = tid; i < 66; i += 256) {
        int gp = p0 - 1 + i; gp = gp < 0 ? 0 : (gp > 4095 ? 4095 : gp);
        int gm = m0 - 1 + i; gm = gm < 0 ? 0 : (gm > 4095 ? 4095 : gm);
        csL[i] = csi[(size_t)b * L + gp];
        inL[i] = invn[(size_t)b * L + gm];
    }
    __syncthreads();

    int il = tid >> 2, seg = tid & 3;
    int zm = il & 15;
    float wm = zm > 0 ? 1.f : 0.f, wp = zm < 15 ? 1.f : 0.f;
    float in_c = inL[il + 1], in_m = inL[il] * wm, in_p = inL[il + 2] * wp;
    int cb = 8 + seg * 16;
    int sb = 1 + seg * 16;
    float az[16];
    #pragma unroll
    for (int j = 0; j < 16; j++) {
        float acc = Eb[(il + 1) * EBC + cb + j] * csL[sb + j] * in_c;
        if (j > 0)
            acc += Eb[il * EBC + cb + j - 1] * csL[sb + j - 1] * in_m;
        if (j < 15)
            acc += Eb[(il + 2) * EBC + cb + j + 1] * csL[sb + j + 1] * in_p;
        az[j] = acc;
    }
    #pragma unroll
    for (int j = 0; j < 16; j++) AZ[il][seg * 16 + j] = az[j];
    __syncthreads();

    int prr = tid >> 2, ms = (tid & 3) * 16;
    float o[16];
    #pragma unroll
    for (int i = 0; i < 16; i++) o[i] = AZ[ms + i][prr];
    uint4* dst = (uint4*)&At[(size_t)(p0 + prr) * L + m0 + ms];
    dst[0] = pack8(o);
    dst[1] = pack8(o + 8);
}

// ---------------------------------------------------------------------------
// K7: per-p-row diag-y/x in transposed space, 3-tap staged clamped loads;
//     p and p+16 per block; XCD owns one py-pair, px innermost (L2-fit).
// ---------------------------------------------------------------------------
__global__ __launch_bounds__(256, 4) void k_diagyx(unsigned short* __restrict__ slab,
                                                   size_t slotU) {
    int zi = blockIdx.z;
    const unsigned short* At = slab + (size_t)zi * slotU;
    unsigned short* Ht = slab + (size_t)zi * slotU + (size_t)L * L;
    int bx = blockIdx.x;
    int xcd = bx & 7;
    int j = bx >> 3;                    // [0,256)
    int jpx = j & 15, jpz = j >> 4;
    int pbase = jpx * 256 + (2 * xcd) * 16 + jpz;   // pairs (pbase, pbase+16)
    int tid = threadIdx.x;
    int mx = tid >> 4, my = tid & 15;

    #pragma unroll 1
    for (int sub = 0; sub < 2; sub++) {
        int p = pbase + 16 * sub;
        int px = p >> 8, py = (p >> 4) & 15;
        int own = p * L + tid * 16;

        float c[16];
        #pragma unroll
        for (int z = 0; z < 16; z++) c[z] = 0.f;

        #pragma unroll
        for (int gx = 0; gx < 3; gx++) {
            int dx = gx - 1;
            uint4 s0[3], s1[3];
            float w3[3];
            #pragma unroll
            for (int gy = 0; gy < 3; gy++) {
                int dy = gy - 1;
                int D = dy * 16 + dx * 256;
                bool ok = (unsigned)(px + dx) < 16u && (unsigned)(mx + dx) < 16u &&
                          (unsigned)(py + dy) < 16u && (unsigned)(my + dy) < 16u;
                int off = ok ? ((p + D) * L + tid * 16 + D) : own;
                const uint4* s4 = (const uint4*)(At + off);
                s0[gy] = s4[0];
                s1[gy] = s4[1];
                w3[gy] = ok ? 1.f : 0.f;
            }
            #pragma unroll
            for (int gy = 0; gy < 3; gy++) {
                float f[16];
                unpack8(s0[gy], f);
                unpack8(s1[gy], f + 8);
                #pragma unroll
                for (int z = 0; z < 16; z++) c[z] += w3[gy] * f[z];
            }
        }
        uint4* dst = (uint4*)&Ht[own];
        dst[0] = pack8(c);
        dst[1] = pack8(c + 8);
    }
}

// ---------------------------------------------------------------------------
// K8: MFMA R[c][p] = sum_m bg[c,m]*H[m,p], split-K=8.
// Ht in slot B; part (f32) into slot A base.
// ---------------------------------------------------------------------------
__global__ __launch_bounds__(256) void k_mm(unsigned short* __restrict__ slab, size_t slotU,
                                            const unsigned short* __restrict__ bgh, int b0) {
    int zi = blockIdx.z, b = b0 + zi;
    const unsigned short* Ht = slab + (size_t)zi * slotU + (size_t)L * L;   // slot B
    float* part = (float*)(slab + (size_t)zi * slotU);                      // slot A
    const unsigned short* bghb = bgh + (size_t)b * NC * L;
    int tid = threadIdx.x;
    int w = tid >> 6, lane = tid & 63;
    int rr = lane & 15, kg = lane >> 4;
    int p0 = blockIdx.x * 64;
    int k0 = blockIdx.y * 512;

    f32x4 acc[4];
    #pragma unroll
    for (int pt = 0; pt < 4; pt++) { acc[pt][0] = 0.f; acc[pt][1] = 0.f; acc[pt][2] = 0.f; acc[pt][3] = 0.f; }

    #pragma unroll 2
    for (int kk = 0; kk < 16; kk++) {
        int kb = k0 + kk * 32 + kg * 8;
        bf16x8 a = *(const bf16x8*)&bghb[(size_t)(w * 16 + rr) * L + kb];
        #pragma unroll
        for (int pt = 0; pt < 4; pt++) {
            bf16x8 bb = *(const bf16x8*)&Ht[(size_t)(p0 + pt * 16 + rr) * L + kb];
            acc[pt] = __builtin_amdgcn_mfma_f32_16x16x32_bf16(a, bb, acc[pt], 0, 0, 0);
        }
    }
    float* pp = part + (size_t)blockIdx.y * NC * L;
    #pragma unroll
    for (int pt = 0; pt < 4; pt++)
        #pragma unroll
        for (int r = 0; r < 4; r++)
            pp[(size_t)(w * 16 + kg * 4 + r) * L + p0 + pt * 16 + rr] = acc[pt][r];
}

// ---------------------------------------------------------------------------
// K9: reduce 8 partials + epilogue (float4).
// ---------------------------------------------------------------------------
__global__ void k_epilogue(unsigned short* __restrict__ slab, size_t slotU,
                           const float* __restrict__ Tbox, const float* __restrict__ mask,
                           const float* __restrict__ fm, float* __restrict__ out, int b0) {
    int zi = blockIdx.z, b = b0 + zi;
    const float* part = (const float*)(slab + (size_t)zi * slotU);
    int idx4 = (blockIdx.x * 256 + threadIdx.x) * 4;
    int p = idx4 & 4095;
    float4 s = make_float4(0.f, 0.f, 0.f, 0.f);
    #pragma unroll
    for (int i = 0; i < 8; i++) {
        float4 v = *(const float4*)(part + (size_t)i * NC * L + idx4);
        s.x += v.x; s.y += v.y; s.z += v.z; s.w += v.w;
    }
    float4 tb = *(const float4*)(Tbox + (size_t)b * L + p);
    float4 mk = *(const float4*)(mask + (size_t)b * L + p);
    float4 fv = *(const float4*)(fm + (size_t)b * NC * L + idx4);
    float4 o;
    o.x = (s.x + 1e-7f * tb.x) * mk.x * (1.f / 27.f) + fv.x * (1.f - mk.x);
    o.y = (s.y + 1e-7f * tb.y) * mk.y * (1.f / 27.f) + fv.y * (1.f - mk.y);
    o.z = (s.z + 1e-7f * tb.z) * mk.z * (1.f / 27.f) + fv.z * (1.f - mk.z);
    o.w = (s.w + 1e-7f * tb.w) * mk.w * (1.f / 27.f) + fv.w * (1.f - mk.w);
    *(float4*)(out + (size_t)b * NC * L + idx4) = o;
}

// ---------------------------------------------------------------------------
extern "C" void kernel_launch(void* const* d_in, const int* in_sizes, int n_in,
                              void* d_out, int out_size, void* d_ws, size_t ws_size,
                              hipStream_t stream) {
    const float* fm = (const float*)d_in[0];
    const float* mask = (const float*)d_in[1];
    float* out = (float*)d_out;

    unsigned short* bgT = (unsigned short*)d_ws;
    unsigned short* fmT = bgT + (size_t)BZ * L * NC;
    unsigned short* bgh = fmT + (size_t)BZ * L * NC;
    float* sfm  = (float*)(bgh + (size_t)BZ * L * NC);
    float* sbg  = sfm + (size_t)BZ * L;
    float* qbg  = sbg + (size_t)BZ * L;
    float* invn = qbg + (size_t)BZ * L;
    float* s2fm = invn + (size_t)BZ * L;
    float* csi  = s2fm + (size_t)BZ * L;
    float* Tarr = csi + (size_t)BZ * L;
    float* Tbox = Tarr + (size_t)BZ * L;
    unsigned short* slab = (unsigned short*)(Tbox + (size_t)BZ * L);

    const size_t slotU = 2 * (size_t)L * L;
    size_t fixedBytes = (char*)slab - (char*)d_ws;
    size_t avail = ws_size > fixedBytes ? ws_size - fixedBytes : 0;
    int ns = (int)(avail / (slotU * sizeof(unsigned short)));
    if (ns >= 4) ns = 4; else if (ns >= 2) ns = 2; else ns = 1;

    k_prep<<<dim3(16, BZ), 256, 0, stream>>>(fm, mask, bgT, fmT, bgh, sfm, sbg, qbg);
    k_stats<<<BZ, 256, 0, stream>>>(sfm, sbg, qbg, invn, s2fm);

    for (int b0 = 0; b0 < BZ; b0 += ns) {
        int nb = (BZ - b0) < ns ? (BZ - b0) : ns;
        // slot A: Czz -> ps/psi -> At -> part ; slot B: E -> Ht
        k_gram<<<dim3(64, 64, nb), 256, 0, stream>>>(bgT, fmT, slab, slotU, b0);
        k_rowE<<<dim3(2048, 1, nb), 256, 0, stream>>>(slab, slotU, s2fm, invn, b0);
        k_colstat_part<<<dim3(2, 64, nb), 256, 0, stream>>>(slab, slotU, invn, b0);
        k_colstat_merge<<<dim3(16, 1, nb), 256, 0, stream>>>(slab, slotU, csi, Tarr, b0);
        k_tbox<<<dim3(1, 1, nb), 256, 0, stream>>>(Tarr, Tbox, b0);
        k_smtp<<<dim3(64, 64, nb), 256, 0, stream>>>(slab, slotU, csi, invn, b0);
        k_diagyx<<<dim3(2048, 1, nb), 256, 0, stream>>>(slab, slotU);
        k_mm<<<dim3(64, 8, nb), 256, 0, stream>>>(slab, slotU, bgh, b0);
        k_epilogue<<<dim3(256, 1, nb), 256, 0, stream>>>(slab, slotU, Tbox, mask, fm, out, b0);
    }
}

// Round 18
// 582.905 us; speedup vs baseline: 1.4474x; 1.4474x over previous
//
#include <hip/hip_runtime.h>
#include <hip/hip_bf16.h>
#include <math.h>

#define L 4096      // 16^3
#define NC 64
#define BZ 4
#define PS 17       // padded z-stride (bank-conflict-free)
#define PXD 272     // 16*PS
#define EBC 82      // smtp LDS row stride

typedef __attribute__((ext_vector_type(8))) short bf16x8;
typedef __attribute__((ext_vector_type(4))) float f32x4;

__device__ inline unsigned short f2bf(float f) {
    unsigned int u = __float_as_uint(f);
    return (unsigned short)((u + 0x7fffu + ((u >> 16) & 1u)) >> 16);   // RNE
}
__device__ inline float bf2f(unsigned int u) { return __uint_as_float(u << 16); }
__device__ inline void unpack8(uint4 v, float* f) {
    f[0] = bf2f(v.x & 0xffffu); f[1] = bf2f(v.x >> 16);
    f[2] = bf2f(v.y & 0xffffu); f[3] = bf2f(v.y >> 16);
    f[4] = bf2f(v.z & 0xffffu); f[5] = bf2f(v.z >> 16);
    f[6] = bf2f(v.w & 0xffffu); f[7] = bf2f(v.w >> 16);
}
__device__ inline uint4 pack8(const float* f) {
    uint4 v;
    v.x = (unsigned)f2bf(f[0]) | ((unsigned)f2bf(f[1]) << 16);
    v.y = (unsigned)f2bf(f[2]) | ((unsigned)f2bf(f[3]) << 16);
    v.z = (unsigned)f2bf(f[4]) | ((unsigned)f2bf(f[5]) << 16);
    v.w = (unsigned)f2bf(f[6]) | ((unsigned)f2bf(f[7]) << 16);
    return v;
}

// ---------------------------------------------------------------------------
// f32 3-axis box filter helpers (k_stats / k_tbox only)
// ---------------------------------------------------------------------------
__device__ void box3_pad(float* A, float* B, int tid, float out[16]) {
    int x = tid >> 4, y = tid & 15;
    int base = x * PXD + y * PS;
    float t[16];
    {
        float line[16];
        #pragma unroll
        for (int z = 0; z < 16; z++) line[z] = A[base + z];
        #pragma unroll
        for (int z = 0; z < 16; z++) {
            float s = line[z];
            if (z > 0)  s += line[z - 1];
            if (z < 15) s += line[z + 1];
            t[z] = s;
        }
    }
    #pragma unroll
    for (int z = 0; z < 16; z++) B[base + z] = t[z];
    __syncthreads();
    #pragma unroll
    for (int z = 0; z < 16; z++) {
        float s = B[base + z];
        if (y > 0)  s += B[base - PS + z];
        if (y < 15) s += B[base + PS + z];
        t[z] = s;
    }
    __syncthreads();
    #pragma unroll
    for (int z = 0; z < 16; z++) A[base + z] = t[z];
    __syncthreads();
    #pragma unroll
    for (int z = 0; z < 16; z++) {
        float s = A[base + z];
        if (x > 0)  s += A[base - PXD + z];
        if (x < 15) s += A[base + PXD + z];
        out[z] = s;
    }
    __syncthreads();
}
__device__ inline void fill_pad(float* A, const float* __restrict__ g, int tid) {
    for (int i = tid; i < 4096; i += 256)
        A[(i >> 8) * PXD + ((i >> 4) & 15) * PS + (i & 15)] = g[i];
    __syncthreads();
}

// ---------------------------------------------------------------------------
// K1: bg=fm*(1-mask); bf16 copies bgT[l][c], fmT[p][c], bgh[c][p]; f32 sums.
// ---------------------------------------------------------------------------
__global__ void k_prep(const float* __restrict__ fm, const float* __restrict__ mask,
                       unsigned short* __restrict__ bgT, unsigned short* __restrict__ fmT,
                       unsigned short* __restrict__ bgh,
                       float* __restrict__ sfm, float* __restrict__ sbg,
                       float* __restrict__ qbg) {
    int b = blockIdx.y;
    int p = blockIdx.x * 256 + threadIdx.x;
    float m = mask[b * L + p];
    float w = 1.f - m;
    float s_f = 0.f, s_b = 0.f, q_b = 0.f;
    const float* fmb = fm + (size_t)b * NC * L + p;
    unsigned short* bghb = bgh + (size_t)b * NC * L + p;
    unsigned short tA[NC], tB[NC];
    #pragma unroll
    for (int c = 0; c < NC; c++) {
        float f = fmb[(size_t)c * L];
        float g = f * w;
        s_f += f; s_b += g; q_b += g * g;
        unsigned short gb = f2bf(g);
        tA[c] = gb;
        tB[c] = f2bf(f);
        bghb[(size_t)c * L] = gb;
    }
    unsigned short* bgTb = bgT + (size_t)b * L * NC + (size_t)p * NC;
    unsigned short* fmTb = fmT + (size_t)b * L * NC + (size_t)p * NC;
    #pragma unroll
    for (int i = 0; i < 8; i++) {
        ((uint4*)bgTb)[i] = ((const uint4*)tA)[i];
        ((uint4*)fmTb)[i] = ((const uint4*)tB)[i];
    }
    sfm[b * L + p] = s_f;
    sbg[b * L + p] = s_b;
    qbg[b * L + p] = q_b;
}

// ---------------------------------------------------------------------------
// K2: invn = rsqrt(box3(qbg)+2e-7*box3(sbg)+1728e-14); s2fm = box3(box3(sfm))
// ---------------------------------------------------------------------------
__global__ void k_stats(const float* __restrict__ sfm, const float* __restrict__ sbg,
                        const float* __restrict__ qbg,
                        float* __restrict__ invn, float* __restrict__ s2fm) {
    __shared__ float A[16 * PXD];
    __shared__ float Bf[16 * PXD];
    int b = blockIdx.x;
    int tid = threadIdx.x;
    int x = tid >> 4, y = tid & 15;
    float Q[16], Sb[16], r[16];

    fill_pad(A, qbg + b * L, tid);
    box3_pad(A, Bf, tid, Q);
    fill_pad(A, sbg + b * L, tid);
    box3_pad(A, Bf, tid, Sb);
    for (int z = 0; z < 16; z++) {
        float denom = Q[z] + 2e-7f * Sb[z] + 1.728e-11f;
        invn[b * L + x * 256 + y * 16 + z] = rsqrtf(denom);
    }
    fill_pad(A, sfm + b * L, tid);
    box3_pad(A, Bf, tid, r);
    int base = x * PXD + y * PS;
    #pragma unroll
    for (int z = 0; z < 16; z++) A[base + z] = r[z];
    __syncthreads();
    box3_pad(A, Bf, tid, r);
    for (int z = 0; z < 16; z++) s2fm[b * L + x * 256 + y * 16 + z] = r[z];
}

// ---------------------------------------------------------------------------
// K3: MFMA Gram + fused diag-z+box-z (9-term LDS read, single sync), bf16 out.
// ---------------------------------------------------------------------------
__global__ __launch_bounds__(256) void k_gram(const unsigned short* __restrict__ bgT,
                                              const unsigned short* __restrict__ fmT,
                                              unsigned short* __restrict__ slab,
                                              size_t slotU, int b0) {
    int zi = blockIdx.z, b = b0 + zi;
    unsigned short* Czz = slab + (size_t)zi * slotU;
    const unsigned short* bgTb = bgT + (size_t)b * L * NC;
    const unsigned short* fmTb = fmT + (size_t)b * L * NC;
    __shared__ float Gs[64][65];
    int tid = threadIdx.x;
    int l0 = blockIdx.y * 64, p0 = blockIdx.x * 64;
    int w = tid >> 6, lane = tid & 63;
    int rr = lane & 15, kg = lane >> 4;

    bf16x8 a0 = *(const bf16x8*)&bgTb[(size_t)(l0 + w * 16 + rr) * NC + kg * 8];
    bf16x8 a1 = *(const bf16x8*)&bgTb[(size_t)(l0 + w * 16 + rr) * NC + 32 + kg * 8];
    f32x4 acc[4];
    #pragma unroll
    for (int pt = 0; pt < 4; pt++) {
        bf16x8 bb0 = *(const bf16x8*)&fmTb[(size_t)(p0 + pt * 16 + rr) * NC + kg * 8];
        bf16x8 bb1 = *(const bf16x8*)&fmTb[(size_t)(p0 + pt * 16 + rr) * NC + 32 + kg * 8];
        f32x4 z; z[0] = 0.f; z[1] = 0.f; z[2] = 0.f; z[3] = 0.f;
        z = __builtin_amdgcn_mfma_f32_16x16x32_bf16(a0, bb0, z, 0, 0, 0);
        z = __builtin_amdgcn_mfma_f32_16x16x32_bf16(a1, bb1, z, 0, 0, 0);
        acc[pt] = z;
    }
    #pragma unroll
    for (int pt = 0; pt < 4; pt++)
        #pragma unroll
        for (int r = 0; r < 4; r++)
            Gs[w * 16 + kg * 4 + r][pt * 16 + rr] = acc[pt][r];
    __syncthreads();

    int row = tid >> 2, cg = (tid & 3) * 16;
    int lz = row & 15;
    float wl0 = lz > 0 ? 1.f : 0.f, wl2 = lz < 15 ? 1.f : 0.f;
    int rm = row > 0 ? row - 1 : 0, rp = row < 63 ? row + 1 : 63;
    float o[16];
    #pragma unroll
    for (int k = 0; k < 16; k++) {
        float v = 0.f;
        #pragma unroll
        for (int e = -1; e <= 1; e++) {
            if (k + e < 0 || k + e > 15) continue;
            #pragma unroll
            for (int d = -1; d <= 1; d++) {
                if (k + e + d < 0 || k + e + d > 15) continue;
                int col = cg + k + e + d;
                if (d == 0)       v += Gs[row][col];
                else if (d == -1) v += wl0 * Gs[rm][col];
                else              v += wl2 * Gs[rp][col];
            }
        }
        o[k] = v;
    }
    uint4* dst = (uint4*)&Czz[(size_t)(l0 + row) * L + p0 + cg];
    dst[0] = pack8(o);
    dst[1] = pack8(o + 8);
}

// ---------------------------------------------------------------------------
// K4: per l-row diag-y/x via 3-tap staged clamped loads (proven no-spill),
//     box-y via shfl, box-x via LDS, logit+exp; rows l and l+16 per block.
// ---------------------------------------------------------------------------
__global__ __launch_bounds__(256, 4) void k_rowE(unsigned short* __restrict__ slab,
                                                 size_t slotU,
                                                 const float* __restrict__ s2fm,
                                                 const float* __restrict__ invn, int b0) {
    __shared__ float A[16 * PXD];
    int zi = blockIdx.z, b = b0 + zi;
    const unsigned short* Czz = slab + (size_t)zi * slotU;
    unsigned short* E = slab + (size_t)zi * slotU + (size_t)L * L;
    int bx = blockIdx.x;
    int i = (bx & 7) * 256 + (bx >> 3);         // XCD-chunked swizzle (bijective on 2048)
    int lbase = ((i >> 4) << 5) + (i & 15);     // pairs (lbase, lbase+16)
    int tid = threadIdx.x;
    int px = tid >> 4, py = tid & 15;

    #pragma unroll 1
    for (int sub = 0; sub < 2; sub++) {
        int l = lbase + 16 * sub;
        int lx = l >> 8, ly = (l >> 4) & 15;
        int own = l * L + px * 256 + py * 16;

        float c[16];
        #pragma unroll
        for (int z = 0; z < 16; z++) c[z] = 0.f;

        #pragma unroll
        for (int gx = 0; gx < 3; gx++) {
            int dx = gx - 1;
            uint4 s0[3], s1[3];
            float w3[3];
            #pragma unroll
            for (int gy = 0; gy < 3; gy++) {
                int dy = gy - 1;
                bool ok = (unsigned)(lx + dx) < 16u && (unsigned)(px + dx) < 16u &&
                          (unsigned)(ly + dy) < 16u && (unsigned)(py + dy) < 16u;
                int off = ok ? ((l + dy * 16 + dx * 256) * L + (px + dx) * 256 + (py + dy) * 16)
                             : own;
                const uint4* s4 = (const uint4*)(Czz + off);
                s0[gy] = s4[0];
                s1[gy] = s4[1];
                w3[gy] = ok ? 1.f : 0.f;
            }
            #pragma unroll
            for (int gy = 0; gy < 3; gy++) {
                float f[16];
                unpack8(s0[gy], f);
                unpack8(s1[gy], f + 8);
                #pragma unroll
                for (int z = 0; z < 16; z++) c[z] += w3[gy] * f[z];
            }
        }
        // box-y via shuffle (py±1 == lane±1)
        float t16[16];
        #pragma unroll
        for (int z = 0; z < 16; z++) {
            float up = __shfl_up(c[z], 1);
            float dn = __shfl_down(c[z], 1);
            float s = c[z];
            if (py > 0)  s += up;
            if (py < 15) s += dn;
            t16[z] = s;
        }
        int base = px * PXD + py * PS;
        #pragma unroll
        for (int z = 0; z < 16; z++) A[base + z] = t16[z];
        __syncthreads();
        float inl = invn[(size_t)b * L + l];
        const float* s2 = s2fm + (size_t)b * L + px * 256 + py * 16;
        float o[16];
        #pragma unroll
        for (int z = 0; z < 16; z++) {      // box-x + logit + exp
            float s = A[base + z];
            if (px > 0)  s += A[base - PXD + z];
            if (px < 15) s += A[base + PXD + z];
            o[z] = __expf((s + 1e-7f * s2[z]) * inl);
        }
        uint4* dst = (uint4*)&E[own];
        dst[0] = pack8(o);
        dst[1] = pack8(o + 8);
        __syncthreads();                    // A reused next iteration
    }
}

// ---------------------------------------------------------------------------
// K5: column sums of E: staged/unrolled loads, partials [64][L] into slot A.
// ---------------------------------------------------------------------------
__global__ void k_colstat_part(unsigned short* __restrict__ slab, size_t slotU,
                               const float* __restrict__ invn, int b0) {
    int zi = blockIdx.z, b = b0 + zi;
    const unsigned short* E = slab + (size_t)zi * slotU + (size_t)L * L;
    float* ps = (float*)(slab + (size_t)zi * slotU);
    float* psi = ps + 64 * (size_t)L;
    int p8 = (blockIdx.x * 256 + threadIdx.x) * 8;
    int lc = blockIdx.y;
    const float* inv = invn + (size_t)b * L + lc * 64;
    float S[8], SI[8];
    #pragma unroll
    for (int j = 0; j < 8; j++) { S[j] = 0.f; SI[j] = 0.f; }
    const unsigned short* eb = E + (size_t)lc * 64 * L + p8;
    for (int i = 0; i < 64; i += 4) {
        uint4 va = *(const uint4*)(eb + (size_t)(i + 0) * L);
        uint4 vb = *(const uint4*)(eb + (size_t)(i + 1) * L);
        uint4 vc = *(const uint4*)(eb + (size_t)(i + 2) * L);
        uint4 vd = *(const uint4*)(eb + (size_t)(i + 3) * L);
        float f[8];
        float iv;
        unpack8(va, f); iv = inv[i];
        #pragma unroll
        for (int j = 0; j < 8; j++) { S[j] += f[j]; SI[j] += f[j] * iv; }
        unpack8(vb, f); iv = inv[i + 1];
        #pragma unroll
        for (int j = 0; j < 8; j++) { S[j] += f[j]; SI[j] += f[j] * iv; }
        unpack8(vc, f); iv = inv[i + 2];
        #pragma unroll
        for (int j = 0; j < 8; j++) { S[j] += f[j]; SI[j] += f[j] * iv; }
        unpack8(vd, f); iv = inv[i + 3];
        #pragma unroll
        for (int j = 0; j < 8; j++) { S[j] += f[j]; SI[j] += f[j] * iv; }
    }
    float4* d0 = (float4*)(ps + (size_t)lc * L + p8);
    float4* d1 = (float4*)(psi + (size_t)lc * L + p8);
    d0[0] = make_float4(S[0], S[1], S[2], S[3]);
    d0[1] = make_float4(S[4], S[5], S[6], S[7]);
    d1[0] = make_float4(SI[0], SI[1], SI[2], SI[3]);
    d1[1] = make_float4(SI[4], SI[5], SI[6], SI[7]);
}

__global__ void k_colstat_merge(unsigned short* __restrict__ slab, size_t slotU,
                                float* __restrict__ csi, float* __restrict__ Tarr, int b0) {
    int zi = blockIdx.z, b = b0 + zi;
    const float* ps = (const float*)(slab + (size_t)zi * slotU);
    const float* psi = ps + 64 * (size_t)L;
    int p = blockIdx.x * 256 + threadIdx.x;
    float s = 0.f, si = 0.f;
    for (int i = 0; i < 64; i++) { s += ps[(size_t)i * L + p]; si += psi[(size_t)i * L + p]; }
    float inv = 1.f / s;
    csi[(size_t)b * L + p] = inv;
    Tarr[(size_t)b * L + p] = si * inv;
}

__global__ void k_tbox(const float* __restrict__ Tarr, float* __restrict__ Tbox, int b0) {
    __shared__ float A[16 * PXD];
    __shared__ float Bf[16 * PXD];
    int b = b0 + blockIdx.z;
    int tid = threadIdx.x;
    fill_pad(A, Tarr + (size_t)b * L, tid);
    float res[16];
    box3_pad(A, Bf, tid, res);
    int x = tid >> 4, y = tid & 15;
    for (int z = 0; z < 16; z++) Tbox[(size_t)b * L + x * 256 + y * 16 + z] = res[z];
}

// ---------------------------------------------------------------------------
// K6 (fused): softmax-apply + diag-z + TRANSPOSE in one tile pass:
//   At[p][m] = sum_dz w * E[m+dz, p+dz] * csi[p+dz] * invn[m+dz]
// ---------------------------------------------------------------------------
__global__ __launch_bounds__(256) void k_smtp(unsigned short* __restrict__ slab,
                                              size_t slotU,
                                              const float* __restrict__ csi,
                                              const float* __restrict__ invn, int b0) {
    __shared__ float Eb[66 * EBC];
    __shared__ float AZ[64][65];
    __shared__ float csL[66];
    __shared__ float inL[66];
    int zi = blockIdx.z, b = b0 + zi;
    const unsigned short* E = slab + (size_t)zi * slotU + (size_t)L * L;
    unsigned short* At = slab + (size_t)zi * slotU;
    int p0 = blockIdx.x * 64, m0 = blockIdx.y * 64;
    int tid = threadIdx.x;

    for (int s = tid; s < 660; s += 256) {
        int r = s / 10, q = s - r * 10;
        int gm = m0 + r - 1; gm = gm < 0 ? 0 : (gm > 4095 ? 4095 : gm);
        int gp = p0 - 8 + q * 8; gp = gp < 0 ? 0 : (gp > 4088 ? 4088 : gp);
        uint4 v = *(const uint4*)(E + (size_t)gm * L + gp);
        float f[8]; unpack8(v, f);
        #pragma unroll
        for (int k = 0; k < 8; k++) Eb[r * EBC + q * 8 + k] = f[k];
    }
    for (int i = tid; i < 66; i += 256) {
        int gp = p0 - 1 + i; gp = gp < 0 ? 0 : (gp > 4095 ? 4095 : gp);
        int gm = m0 - 1 + i; gm = gm < 0 ? 0 : (gm > 4095 ? 4095 : gm);
        csL[i] = csi[(size_t)b * L + gp];
        inL[i] = invn[(size_t)b * L + gm];
    }
    __syncthreads();

    int il = tid >> 2, seg = tid & 3;
    int zm = il & 15;
    float wm = zm > 0 ? 1.f : 0.f, wp = zm < 15 ? 1.f : 0.f;
    float in_c = inL[il + 1], in_m = inL[il] * wm, in_p = inL[il + 2] * wp;
    int cb = 8 + seg * 16;
    int sb = 1 + seg * 16;
    float az[16];
    #pragma unroll
    for (int j = 0; j < 16; j++) {
        float acc = Eb[(il + 1) * EBC + cb + j] * csL[sb + j] * in_c;
        if (j > 0)
            acc += Eb[il * EBC + cb + j - 1] * csL[sb + j - 1] * in_m;
        if (j < 15)
            acc += Eb[(il + 2) * EBC + cb + j + 1] * csL[sb + j + 1] * in_p;
        az[j] = acc;
    }
    #pragma unroll
    for (int j = 0; j < 16; j++) AZ[il][seg * 16 + j] = az[j];
    __syncthreads();

    int prr = tid >> 2, ms = (tid & 3) * 16;
    float o[16];
    #pragma unroll
    for (int i = 0; i < 16; i++) o[i] = AZ[ms + i][prr];
    uint4* dst = (uint4*)&At[(size_t)(p0 + prr) * L + m0 + ms];
    dst[0] = pack8(o);
    dst[1] = pack8(o + 8);
}

// ---------------------------------------------------------------------------
// K7: per-p-row diag-y/x in transposed space, 3-tap staged clamped loads
//     (proven no-spill form); each block does p and p+16 sequentially.
// ---------------------------------------------------------------------------
__global__ __launch_bounds__(256, 4) void k_diagyx(unsigned short* __restrict__ slab,
                                                   size_t slotU) {
    int zi = blockIdx.z;
    const unsigned short* At = slab + (size_t)zi * slotU;
    unsigned short* Ht = slab + (size_t)zi * slotU + (size_t)L * L;
    int bx = blockIdx.x;
    int i = (bx & 7) * 256 + (bx >> 3);         // XCD-chunked swizzle (bijective on 2048)
    int pbase = ((i >> 4) << 5) + (i & 15);     // pairs (pbase, pbase+16)
    int tid = threadIdx.x;
    int mx = tid >> 4, my = tid & 15;

    #pragma unroll 1
    for (int sub = 0; sub < 2; sub++) {
        int p = pbase + 16 * sub;
        int px = p >> 8, py = (p >> 4) & 15;
        int own = p * L + tid * 16;

        float c[16];
        #pragma unroll
        for (int z = 0; z < 16; z++) c[z] = 0.f;

        #pragma unroll
        for (int gx = 0; gx < 3; gx++) {
            int dx = gx - 1;
            uint4 s0[3], s1[3];
            float w3[3];
            #pragma unroll
            for (int gy = 0; gy < 3; gy++) {
                int dy = gy - 1;
                int D = dy * 16 + dx * 256;
                bool ok = (unsigned)(px + dx) < 16u && (unsigned)(mx + dx) < 16u &&
                          (unsigned)(py + dy) < 16u && (unsigned)(my + dy) < 16u;
                int off = ok ? ((p + D) * L + tid * 16 + D) : own;
                const uint4* s4 = (const uint4*)(At + off);
                s0[gy] = s4[0];
                s1[gy] = s4[1];
                w3[gy] = ok ? 1.f : 0.f;
            }
            #pragma unroll
            for (int gy = 0; gy < 3; gy++) {
                float f[16];
                unpack8(s0[gy], f);
                unpack8(s1[gy], f + 8);
                #pragma unroll
                for (int z = 0; z < 16; z++) c[z] += w3[gy] * f[z];
            }
        }
        uint4* dst = (uint4*)&Ht[own];
        dst[0] = pack8(c);
        dst[1] = pack8(c + 8);
    }
}

// ---------------------------------------------------------------------------
// K8: MFMA R[c][p] = sum_m bg[c,m]*H[m,p], split-K=8.
// Ht in slot B; part (f32) into slot A base.
// ---------------------------------------------------------------------------
__global__ __launch_bounds__(256) void k_mm(unsigned short* __restrict__ slab, size_t slotU,
                                            const unsigned short* __restrict__ bgh, int b0) {
    int zi = blockIdx.z, b = b0 + zi;
    const unsigned short* Ht = slab + (size_t)zi * slotU + (size_t)L * L;   // slot B
    float* part = (float*)(slab + (size_t)zi * slotU);                      // slot A
    const unsigned short* bghb = bgh + (size_t)b * NC * L;
    int tid = threadIdx.x;
    int w = tid >> 6, lane = tid & 63;
    int rr = lane & 15, kg = lane >> 4;
    int p0 = blockIdx.x * 64;
    int k0 = blockIdx.y * 512;

    f32x4 acc[4];
    #pragma unroll
    for (int pt = 0; pt < 4; pt++) { acc[pt][0] = 0.f; acc[pt][1] = 0.f; acc[pt][2] = 0.f; acc[pt][3] = 0.f; }

    #pragma unroll 2
    for (int kk = 0; kk < 16; kk++) {
        int kb = k0 + kk * 32 + kg * 8;
        bf16x8 a = *(const bf16x8*)&bghb[(size_t)(w * 16 + rr) * L + kb];
        #pragma unroll
        for (int pt = 0; pt < 4; pt++) {
            bf16x8 bb = *(const bf16x8*)&Ht[(size_t)(p0 + pt * 16 + rr) * L + kb];
            acc[pt] = __builtin_amdgcn_mfma_f32_16x16x32_bf16(a, bb, acc[pt], 0, 0, 0);
        }
    }
    float* pp = part + (size_t)blockIdx.y * NC * L;
    #pragma unroll
    for (int pt = 0; pt < 4; pt++)
        #pragma unroll
        for (int r = 0; r < 4; r++)
            pp[(size_t)(w * 16 + kg * 4 + r) * L + p0 + pt * 16 + rr] = acc[pt][r];
}

// ---------------------------------------------------------------------------
// K9: reduce 8 partials + epilogue (float4). part in slot A base.
// ---------------------------------------------------------------------------
__global__ void k_epilogue(unsigned short* __restrict__ slab, size_t slotU,
                           const float* __restrict__ Tbox, const float* __restrict__ mask,
                           const float* __restrict__ fm, float* __restrict__ out, int b0) {
    int zi = blockIdx.z, b = b0 + zi;
    const float* part = (const float*)(slab + (size_t)zi * slotU);
    int idx4 = (blockIdx.x * 256 + threadIdx.x) * 4;
    int p = idx4 & 4095;
    float4 s = make_float4(0.f, 0.f, 0.f, 0.f);
    #pragma unroll
    for (int i = 0; i < 8; i++) {
        float4 v = *(const float4*)(part + (size_t)i * NC * L + idx4);
        s.x += v.x; s.y += v.y; s.z += v.z; s.w += v.w;
    }
    float4 tb = *(const float4*)(Tbox + (size_t)b * L + p);
    float4 mk = *(const float4*)(mask + (size_t)b * L + p);
    float4 fv = *(const float4*)(fm + (size_t)b * NC * L + idx4);
    float4 o;
    o.x = (s.x + 1e-7f * tb.x) * mk.x * (1.f / 27.f) + fv.x * (1.f - mk.x);
    o.y = (s.y + 1e-7f * tb.y) * mk.y * (1.f / 27.f) + fv.y * (1.f - mk.y);
    o.z = (s.z + 1e-7f * tb.z) * mk.z * (1.f / 27.f) + fv.z * (1.f - mk.z);
    o.w = (s.w + 1e-7f * tb.w) * mk.w * (1.f / 27.f) + fv.w * (1.f - mk.w);
    *(float4*)(out + (size_t)b * NC * L + idx4) = o;
}

// ---------------------------------------------------------------------------
extern "C" void kernel_launch(void* const* d_in, const int* in_sizes, int n_in,
                              void* d_out, int out_size, void* d_ws, size_t ws_size,
                              hipStream_t stream) {
    const float* fm = (const float*)d_in[0];
    const float* mask = (const float*)d_in[1];
    float* out = (float*)d_out;

    unsigned short* bgT = (unsigned short*)d_ws;
    unsigned short* fmT = bgT + (size_t)BZ * L * NC;
    unsigned short* bgh = fmT + (size_t)BZ * L * NC;
    float* sfm  = (float*)(bgh + (size_t)BZ * L * NC);
    float* sbg  = sfm + (size_t)BZ * L;
    float* qbg  = sbg + (size_t)BZ * L;
    float* invn = qbg + (size_t)BZ * L;
    float* s2fm = invn + (size_t)BZ * L;
    float* csi  = s2fm + (size_t)BZ * L;
    float* Tarr = csi + (size_t)BZ * L;
    float* Tbox = Tarr + (size_t)BZ * L;
    unsigned short* slab = (unsigned short*)(Tbox + (size_t)BZ * L);

    const size_t slotU = 2 * (size_t)L * L;
    size_t fixedBytes = (char*)slab - (char*)d_ws;
    size_t avail = ws_size > fixedBytes ? ws_size - fixedBytes : 0;
    int ns = (int)(avail / (slotU * sizeof(unsigned short)));
    if (ns >= 4) ns = 4; else if (ns >= 2) ns = 2; else ns = 1;

    k_prep<<<dim3(16, BZ), 256, 0, stream>>>(fm, mask, bgT, fmT, bgh, sfm, sbg, qbg);
    k_stats<<<BZ, 256, 0, stream>>>(sfm, sbg, qbg, invn, s2fm);

    for (int b0 = 0; b0 < BZ; b0 += ns) {
        int nb = (BZ - b0) < ns ? (BZ - b0) : ns;
        // slot A: Czz -> ps/psi -> At -> part ; slot B: E -> Ht
        k_gram<<<dim3(64, 64, nb), 256, 0, stream>>>(bgT, fmT, slab, slotU, b0);
        k_rowE<<<dim3(2048, 1, nb), 256, 0, stream>>>(slab, slotU, s2fm, invn, b0);
        k_colstat_part<<<dim3(2, 64, nb), 256, 0, stream>>>(slab, slotU, invn, b0);
        k_colstat_merge<<<dim3(16, 1, nb), 256, 0, stream>>>(slab, slotU, csi, Tarr, b0);
        k_tbox<<<dim3(1, 1, nb), 256, 0, stream>>>(Tarr, Tbox, b0);
        k_smtp<<<dim3(64, 64, nb), 256, 0, stream>>>(slab, slotU, csi, invn, b0);
        k_diagyx<<<dim3(2048, 1, nb), 256, 0, stream>>>(slab, slotU);
        k_mm<<<dim3(64, 8, nb), 256, 0, stream>>>(slab, slotU, bgh, b0);
        k_epilogue<<<dim3(256, 1, nb), 256, 0, stream>>>(slab, slotU, Tbox, mask, fm, out, b0);
    }
}